// Round 5
// baseline (147.683 us; speedup 1.0000x reference)
//
#include <hip/hip_runtime.h>

// Bilinear backward warp: img [B,C,H,W] f32, flo [B,2,H,W] f32 -> out [B,C,H,W] f32
// B=8, C=64, H=256, W=448
//
// R5: 2-buffer LDS pipeline, stage(c+1) issued at TOP of iteration c, counted
// s_waitcnt vmcnt(4) at BOTTOM (3 stage loads + 4 stores per iter; vmcnt(4)
// retires exactly the 3 stage loads, leaves this iter's stores in flight).
// Linear LDS (no swizzle) -> ds_read2_b32 pair fusion. 43KB LDS -> 3 blocks/CU;
// channel-split (32 ch/block, grid=1024) so 3 blocks are resident.

#define BN 8
#define CN 64
#define HN 256
#define WN 448
#define HW (HN * WN)
#define R 4              // output rows per block
#define BAND 12          // staged rows: lo = h0-4 .. h0+7
#define NBUF 2
#define TPB WN           // 448 threads = 7 waves
#define NXCD 8
#define CSPLIT 2
#define CLOOP (CN / CSPLIT)   // 32 channels per block

typedef __attribute__((address_space(1))) const void glb_v;
typedef __attribute__((address_space(3))) void lds_v;

__global__ __launch_bounds__(TPB) void warp_kernel(const float* __restrict__ img,
                                                   const float* __restrict__ flo,
                                                   float* __restrict__ out) {
    __shared__ float lds[NBUF][BAND * WN + 4];   // +4 pad for x1 read at corner

    // XCD swizzle: 1024 blocks = 128/XCD; XCD k owns batch k (tiles in order,
    // the two channel-halves of a tile adjacent -> share L2 bands).
    const int nwg = gridDim.x;            // 1024
    const int cpx = nwg / NXCD;           // 128
    const int bid = blockIdx.x;
    const int wgid = (bid % NXCD) * cpx + (bid / NXCD);

    const int b    = wgid / cpx;          // 0..7 (cpx == blocks per batch)
    const int rem  = wgid % cpx;          // 0..127
    const int tile = rem >> 1;            // 0..63
    const int c0   = (rem & 1) * CLOOP;   // 0 or 32
    const int h0   = tile * R;
    const int w    = threadIdx.x;         // 0..447

    int lo = h0 - 4;
    lo = lo < 0 ? 0 : (lo > HN - BAND ? HN - BAND : lo);

    const float* imgb = img + (size_t)b * CN * HW;
    const float* flob = flo + (size_t)b * 2 * HW;

    // ---- per-pixel setup, channel-invariant ----
    float wa[R], wb[R], wc[R], wd[R];
    int sA[R], sB[R];       // band-relative LDS word offsets (row clamped into band)
    int gA[R], gB[R];       // plane-relative global word offsets (fallback)
    int dx_[R];
    bool fb[R];
    bool anyfb = false;
#pragma unroll
    for (int r = 0; r < R; ++r) {
        const int h = h0 + r;
        const int hw = h * WN + w;
        const float fx = flob[hw];
        const float fy = flob[HW + hw];
        const float x = (float)w + fx;
        const float y = (float)h + fy;
        int x0 = (int)x;                 // trunc toward zero (matches ref)
        int x1 = x0 + 1;
        int y0 = (int)y;
        int y1 = y0 + 1;
        x0 = min(max(x0, 0), WN - 1);
        x1 = min(max(x1, 0), WN - 1);
        y0 = min(max(y0, 0), HN - 1);
        y1 = min(max(y1, 0), HN - 1);
        const float x0f = (float)x0, x1f = (float)x1;
        const float y0f = (float)y0, y1f = (float)y1;
        wa[r] = (x1f - x) * (y1f - y);
        wb[r] = (x1f - x) * (y - y0f);
        wc[r] = (x - x0f) * (y1f - y);
        wd[r] = (x - x0f) * (y - y0f);
        dx_[r] = x1 - x0;                // 0 only at l/r edge clip
        const bool inband = (y0 >= lo) && (y1 <= lo + BAND - 1);
        fb[r] = !inband;
        anyfb |= fb[r];
        const int rA = min(max(y0 - lo, 0), BAND - 1);
        const int rB = min(max(y1 - lo, 0), BAND - 1);
        sA[r] = rA * WN + x0;
        sB[r] = rB * WN + x0;
        gA[r] = y0 * WN + x0;
        gB[r] = y1 * WN + x0;
    }
    const bool dirty = __any(anyfb);    // wave-uniform, P(dirty wave) ~ 1%

    // ---- staging: BAND*WN = 5376 words = 21 x 1KB chunks, 3 per wave ----
    const int wv = threadIdx.x >> 6;    // 0..6
    const int lane = threadIdx.x & 63;
    const int srcw = wv * 768 + lane * 4;       // word offset of chunk 0
    const int dstb = wv * 3072 + lane * 16;     // byte offset of chunk 0

    auto stage = [&](int bufi, int c) {         // c = global channel
        const float* s0 = imgb + (size_t)c * HW + (size_t)lo * WN + srcw;
        char* d0 = (char*)&lds[bufi][0] + dstb;
        __builtin_amdgcn_global_load_lds((glb_v*)(s0),       (lds_v*)(d0),        16, 0, 0);
        __builtin_amdgcn_global_load_lds((glb_v*)(s0 + 256), (lds_v*)(d0 + 1024), 16, 0, 0);
        __builtin_amdgcn_global_load_lds((glb_v*)(s0 + 512), (lds_v*)(d0 + 2048), 16, 0, 0);
    };

    stage(0, c0);
    asm volatile("s_waitcnt vmcnt(0)" ::: "memory");
    __builtin_amdgcn_s_barrier();

    float* outp = out + (size_t)b * CN * HW + (size_t)c0 * HW + (size_t)h0 * WN + w;

    for (int cl = 0; cl < CLOOP; ++cl) {
        if (cl + 1 < CLOOP) stage((cl + 1) & 1, c0 + cl + 1);

        const float* buf = &lds[cl & 1][0];
        float o[R];
        if (!dirty) {
#pragma unroll
            for (int r = 0; r < R; ++r) {
                const float a0 = buf[sA[r]];
                const float a1 = buf[sA[r] + 1];   // ds_read2_b32 with a0
                const float b0 = buf[sB[r]];
                const float b1 = buf[sB[r] + 1];
                const float Ic = dx_[r] ? a1 : a0;
                const float Id = dx_[r] ? b1 : b0;
                o[r] = wa[r] * a0 + wb[r] * b0 + wc[r] * Ic + wd[r] * Id;
            }
        } else {
            const float* pg = imgb + (size_t)(c0 + cl) * HW;
#pragma unroll
            for (int r = 0; r < R; ++r) {
                float a0 = buf[sA[r]];
                float a1 = buf[sA[r] + 1];
                float b0 = buf[sB[r]];
                float b1 = buf[sB[r] + 1];
                if (fb[r]) {
                    a0 = pg[gA[r]];
                    a1 = pg[gA[r] + dx_[r]];
                    b0 = pg[gB[r]];
                    b1 = pg[gB[r] + dx_[r]];
                }
                const float Ic = dx_[r] ? a1 : a0;
                const float Id = dx_[r] ? b1 : b0;
                o[r] = wa[r] * a0 + wb[r] * b0 + wc[r] * Ic + wd[r] * Id;
            }
        }
#pragma unroll
        for (int r = 0; r < R; ++r) {
            outp[(size_t)cl * HW + r * WN] = o[r];
        }

        if (cl + 1 < CLOOP) {
            // FIFO: [<=4 stores(cl-1)][3 loads stage(cl+1)][4 stores(cl)]
            // vmcnt(4) retires through the stage loads; stores(cl) stay in flight.
            asm volatile("s_waitcnt vmcnt(4)" ::: "memory");
            __builtin_amdgcn_s_barrier();
        }
    }
}

extern "C" void kernel_launch(void* const* d_in, const int* in_sizes, int n_in,
                              void* d_out, int out_size, void* d_ws, size_t ws_size,
                              hipStream_t stream) {
    const float* img = (const float*)d_in[0];
    const float* flo = (const float*)d_in[1];
    float* out = (float*)d_out;

    const int grid = BN * (HN / R) * CSPLIT;   // 1024 blocks
    warp_kernel<<<grid, TPB, 0, stream>>>(img, flo, out);
}